// Round 4
// baseline (2040.303 us; speedup 1.0000x reference)
//
#include <hip/hip_runtime.h>
#include <hip/hip_bf16.h>

// GraphSage: 3x SAGEConv(mean) + linear head.
// r21: cache-blocked LDS-scatter aggregate (replaces gather-per-node).
//   - Each block owns a 32-node dst GROUP with an f32 accum tile in LDS
//     (16KB, col-interleaved layout -> ds_add_f32 2 lanes/bank = free).
//   - Edges per group are COARSELY sorted by src>>8 (counting sort, 256-node
//     windows) in k_bucket_csr: each block sweeps the 12.8MB feature table
//     monotonically; 1568 equal-work blocks (512 +/- 22 edges) all resident
//     (8 blocks/CU) stay progress-aligned -> gathers hit a sliding L2 window.
//   - r20 POST-MORTEM: per-node insertion sort cost +44us (divergent LDS
//     O(deg^2), 1.6M bank conflicts) and gained 0 — per-node sorted lists
//     do NOT form a window (degree variance disperses wave progress). The
//     window must be block-level with equal-work blocks. Reverted.
//   - CSR build SIMPLER than r19: no per-node segments, no row_start, no
//     per-node padding. Per-group edge lists padded to mult 16 with sentinel
//     src=NN (zero row, L1-resident; adds 0.0 to a real node = harmless).
//   - cnt[] (mean divisor) still from per-node histogram.
// r19 carried: GEMM double-buffered A-prefetch across grid-stride loop
//   (load-bearing: keeps 128-VGPR B set live); s_lo plane dropped (mean is
//   bf16-precision anyway); head fused into layer-2 GEMM; launches = 10.
// Structure: SEPARATE aggregate and GEMM (r12 fusion starved the gather).
// XCD affinity NOT controllable from HIP (r14/r15) — do not retry.
// fp8 gather REJECTED: mean-of-16 e4m3 noise ~4.3e-3 > 3.85e-3 threshold.
// packed[] aliases s_hi (disjoint lifetime: consumed by bucket_csr pre-agg).

constexpr int NN = 50000;
constexpr int NE = 800000;
constexpr int NTILE = NN / 16;          // 3125 exact
constexpr int EPB = 4096;
constexpr int NBLK = (NE + EPB - 1) / EPB;   // 196
constexpr int NBUCK = 196;                   // ceil(NN/256)
constexpr int BCAP = 6144;   // packed bucket capacity (edges); mean 4096
constexpr int NGRP = NBUCK * 8;              // 1568 groups of 32 dst nodes
constexpr int HCAP = 768;    // edges per group cap; mean 512, sigma~22 (+11s), mult 16
constexpr int GGRID = 512;   // GEMM grid (2 blocks/CU)

using bf16x8 = __attribute__((ext_vector_type(8))) short;
using f32x4  = __attribute__((ext_vector_type(4))) float;

__device__ __forceinline__ unsigned short bf16_rne(float f) {
    unsigned u = __float_as_uint(f);
    unsigned r = (u + 0x7FFFu + ((u >> 16) & 1u)) >> 16;
    return (unsigned short)r;
}
__device__ __forceinline__ float bf16_f(unsigned short h) {
    return __uint_as_float(((unsigned)h) << 16);
}
__device__ __forceinline__ unsigned pack_split(float v) {
    unsigned short hi = bf16_rne(v);
    float r = v - bf16_f(hi);
    unsigned short lo = bf16_rne(r);
    return (((unsigned)hi) << 16) | (unsigned)lo;
}

// ------------- pack x -> planar split bf16, + all init work ---------------

__global__ __launch_bounds__(256) void k_packinit(const float* __restrict__ x,
        unsigned short* __restrict__ hhi, unsigned short* __restrict__ hlo,
        float* __restrict__ out, const float* __restrict__ bf,
        int* __restrict__ bcnt) {
    int i = blockIdx.x * blockDim.x + threadIdx.x;
    constexpr int TOT = NN * 128 / 4;
    if (i < TOT) {
        float4 v = ((const float4*)x)[i];
        unsigned p0 = pack_split(v.x), p1 = pack_split(v.y);
        unsigned p2 = pack_split(v.z), p3 = pack_split(v.w);
        uint2 hi, lo;
        hi.x = (p0 >> 16) | (p1 & 0xFFFF0000u);
        hi.y = (p2 >> 16) | (p3 & 0xFFFF0000u);
        lo.x = (p0 & 0xFFFFu) | (p1 << 16);
        lo.y = (p2 & 0xFFFFu) | (p3 << 16);
        ((uint2*)hhi)[i] = hi;
        ((uint2*)hlo)[i] = lo;
    }
    if (i < NN) out[i] = bf[0];
    if (i < 256) bcnt[i] = 0;
    if (i < 128) hhi[(size_t)NN * 128 + i] = 0;   // sentinel row for pad edges
}

// ---------------- CSR build: one-pass bucket scatter ----------------

__global__ __launch_bounds__(256) void k_build_buckets(const int* __restrict__ ei,
        int* __restrict__ bcnt, unsigned* __restrict__ packed) {
    __shared__ unsigned stage[EPB];   // 16KB
    __shared__ int h[256];
    __shared__ int cur[256];
    int t = threadIdx.x;
    h[t] = 0;
    __syncthreads();
    int e0 = blockIdx.x * EPB;
    int e1 = e0 + EPB; if (e1 > NE) e1 = NE;
    for (int e = e0 + t; e < e1; e += 256) {
        int s = ei[e];
        int d = ei[NE + e];
        stage[e - e0] = ((unsigned)d << 16) | (unsigned)s;
        atomicAdd(&h[d >> 8], 1);
    }
    __syncthreads();
    if (t < NBUCK) cur[t] = t * BCAP + atomicAdd(&bcnt[t], h[t]);
    __syncthreads();
    for (int e = e0 + t; e < e1; e += 256) {
        unsigned r = stage[e - e0];
        int pos = atomicAdd(&cur[r >> 24], 1);   // bucket = d>>8 = r>>24
        packed[pos] = r;
    }
}

// Per dst-bucket (256 nodes): per-node counts (mean divisor) + counting sort
// of edges into 8 dst-GROUPS of 32 nodes, each coarsely ordered by src>>8
// (256-node src windows). Records out: (src<<8) | (dst&31). Group lists
// padded to mult 16 with sentinel (NN<<8).
__global__ __launch_bounds__(256) void k_bucket_csr(const unsigned* __restrict__ packed,
        const int* __restrict__ bcnt, unsigned* __restrict__ perm32,
        int* __restrict__ cnt, int* __restrict__ ecnt) {
    __shared__ unsigned recs[BCAP];   // 24KB
    __shared__ int bins[8][256];      // 8KB: [group][src>>8] hist -> cursors
    __shared__ int ncnt[256];         // per-node counts; reused for Lg/Lp stage
    int b = blockIdx.x;
    int m = bcnt[b]; if (m > BCAP) m = BCAP;
    int t = threadIdx.x;
    ncnt[t] = 0;
#pragma unroll
    for (int g = 0; g < 8; ++g) bins[g][t] = 0;
    __syncthreads();
    int lo = b * BCAP;
    for (int i = t; i < m; i += 256) {
        unsigned r = packed[lo + i];
        recs[i] = r;
        unsigned d8 = (r >> 16) & 255;
        atomicAdd(&ncnt[d8], 1);
        atomicAdd(&bins[d8 >> 5][(r & 0xFFFFu) >> 8], 1);
    }
    __syncthreads();
    int node = b * 256 + t;
    if (node < NN) cnt[node] = ncnt[t];
    // per-group exclusive scan over the 256 src-bins.
    // wave w: lanes 0..31 -> group 2w, lanes 32..63 -> group 2w+1.
    int lane = t & 63, wave = t >> 6;
    int g = wave * 2 + (lane >> 5);
    int l5 = lane & 31;
    int loc[8];
    int tot = 0;
#pragma unroll
    for (int k = 0; k < 8; ++k) {
        int c = bins[g][l5 * 8 + k];
        loc[k] = tot; tot += c;
    }
    int v = tot;
    for (int o = 1; o < 32; o <<= 1) { int u = __shfl_up(v, o, 32); if (l5 >= o) v += u; }
    int ex = v - tot;                       // exclusive across lanes (width 32)
    __syncthreads();
#pragma unroll
    for (int k = 0; k < 8; ++k) bins[g][l5 * 8 + k] = ex + loc[k];
    __syncthreads();
    // scatter to per-group fixed regions
    for (int i = t; i < m; i += 256) {
        unsigned r = recs[i];
        unsigned s = r & 0xFFFFu;
        unsigned d8 = (r >> 16) & 255;
        int gg = d8 >> 5;
        int pos = atomicAdd(&bins[gg][s >> 8], 1);
        perm32[(size_t)(b * 8 + gg) * HCAP + pos] = (s << 8) | (d8 & 31);
    }
    __syncthreads();
    if (t < 8) {
        int Lg = bins[t][255];              // cursor past last bin = group total
        int Lp = (Lg + 15) & ~15;
        if (Lp > HCAP) Lp = HCAP;
        ecnt[b * 8 + t] = Lp;
        ncnt[t] = Lg;
        ncnt[8 + t] = Lp;
    }
    __syncthreads();
#pragma unroll
    for (int gg = 0; gg < 8; ++gg) {
        int Lg = ncnt[gg], Lp = ncnt[8 + gg];
        for (int i = Lg + t; i < Lp; i += 256)
            perm32[(size_t)(b * 8 + gg) * HCAP + i] = ((unsigned)NN << 8);
    }
}

// ---------------- pack all 3 layers' weights (1 kernel) ----------------

__global__ __launch_bounds__(256) void k_pack_w3(
        const float* __restrict__ Wl0, const float* __restrict__ Wr0,
        const float* __restrict__ Wl1, const float* __restrict__ Wr1,
        const float* __restrict__ Wl2, const float* __restrict__ Wr2,
        unsigned short* __restrict__ whi, unsigned short* __restrict__ wlo) {
    int layer = blockIdx.x >> 7;
    int i = (blockIdx.x & 127) * 256 + threadIdx.x;     // 0..32767
    const float* Wl = (layer == 0) ? Wl0 : (layer == 1) ? Wl1 : Wl2;
    const float* Wr = (layer == 0) ? Wr0 : (layer == 1) ? Wr1 : Wr2;
    int c = i >> 8;
    int k = i & 255;
    float v = (k < 128) ? Wl[c * 128 + k] : Wr[c * 128 + (k - 128)];
    unsigned short hi = bf16_rne(v);
    whi[layer * 32768 + i] = hi;
    wlo[layer * 32768 + i] = bf16_rne(v - bf16_f(hi));
}

// ---------------- aggregate: cache-blocked LDS scatter-mean ----------------
// Block = one 32-node dst group, f32 accum tile in LDS (16KB). Edges coarsely
// src-sorted -> monotone sweep of the feature table; all 1568 blocks resident
// and equal-work -> sliding L2 window. Per edge: 1 u32/lane gather (full
// 256B row per instr) + 2 ds_add_f32 (lane-consecutive -> conflict-free).
// LDS layout: acc[node][IDX(col)], IDX(c) = ((c&1)<<6) | (c>>1): col 2l -> l,
// col 2l+1 -> 64+l, so both adds per edge are lane-linear.
__global__ __launch_bounds__(256) void k_aggregate(const unsigned short* __restrict__ hhi,
        const int* __restrict__ cnt, const unsigned* __restrict__ perm32,
        const int* __restrict__ ecnt, unsigned short* __restrict__ shi) {
    __shared__ float sAcc[32 * 128];   // 16KB
    int g = blockIdx.x;
    int t = threadIdx.x;
#pragma unroll
    for (int i = t; i < 32 * 128; i += 256) sAcc[i] = 0.f;
    int wave = __builtin_amdgcn_readfirstlane(threadIdx.x >> 6);
    int lane = threadIdx.x & 63;
    int ne = ecnt[g];                               // multiple of 16
    const uint4* pr = (const uint4*)(perm32 + (size_t)g * HCAP);
    const unsigned* base32 = (const unsigned*)hhi;  // row stride 64 u32
    __syncthreads();
    int nIter = ne >> 4;                            // 16 edges/iter (4/wave)
    uint4 R = (nIter > 0) ? pr[wave] : make_uint4(0, 0, 0, 0);
    for (int i = 0; i < nIter; ++i) {
        uint4 Rn = R;
        if (i + 1 < nIter) Rn = pr[(i + 1) * 4 + wave];
        unsigned q0 = base32[(size_t)(R.x >> 8) * 64 + lane];
        unsigned q1 = base32[(size_t)(R.y >> 8) * 64 + lane];
        unsigned q2 = base32[(size_t)(R.z >> 8) * 64 + lane];
        unsigned q3 = base32[(size_t)(R.w >> 8) * 64 + lane];
        int d0 = (int)(R.x & 31) * 128;
        int d1 = (int)(R.y & 31) * 128;
        int d2 = (int)(R.z & 31) * 128;
        int d3 = (int)(R.w & 31) * 128;
        atomicAdd(&sAcc[d0 + lane],      __uint_as_float(q0 << 16));
        atomicAdd(&sAcc[d0 + 64 + lane], __uint_as_float(q0 & 0xFFFF0000u));
        atomicAdd(&sAcc[d1 + lane],      __uint_as_float(q1 << 16));
        atomicAdd(&sAcc[d1 + 64 + lane], __uint_as_float(q1 & 0xFFFF0000u));
        atomicAdd(&sAcc[d2 + lane],      __uint_as_float(q2 << 16));
        atomicAdd(&sAcc[d2 + 64 + lane], __uint_as_float(q2 & 0xFFFF0000u));
        atomicAdd(&sAcc[d3 + lane],      __uint_as_float(q3 << 16));
        atomicAdd(&sAcc[d3 + 64 + lane], __uint_as_float(q3 & 0xFFFF0000u));
        R = Rn;
    }
    __syncthreads();
    // write out: thread -> (node = t>>3, seg = t&7); 8 u32 words per thread.
    int node = t >> 3, seg = t & 7;
    int gnode = (g >> 3) * 256 + (g & 7) * 32 + node;
    if (gnode < NN) {
        int deg = cnt[gnode];
        float inv = 1.0f / (float)(deg > 1 ? deg : 1);
        const float* a = &sAcc[node * 128];
        unsigned w[8];
#pragma unroll
        for (int j = 0; j < 8; ++j) {
            float fe = a[seg * 8 + j] * inv;        // col 16*seg + 2j
            float fo = a[64 + seg * 8 + j] * inv;   // col 16*seg + 2j + 1
            w[j] = (unsigned)bf16_rne(fe) | ((unsigned)bf16_rne(fo) << 16);
        }
        uint4* orow = (uint4*)(shi + (size_t)gnode * 128);
        orow[seg * 2]     = make_uint4(w[0], w[1], w[2], w[3]);
        orow[seg * 2 + 1] = make_uint4(w[4], w[5], w[6], w[7]);
    }
}

// ---------------- weight-stationary MFMA GEMM (pipelined grid-stride) ------
// out[n][c] = relu( bias[c] + sum_k [S|H][n][k] W[c][k] )
// A = {s_hi (mean, bf16), h_hi+h_lo (x, split)}. 12 dwordx4 A loads/tile,
// double-buffered across the grid-stride loop (prefetch t+512 before MFMA(t)).
#define GEMM_PROLOG \
    int wave = __builtin_amdgcn_readfirstlane(threadIdx.x >> 6); \
    int lane = threadIdx.x & 63; \
    int row = lane & 15; \
    int kb = lane >> 4; \
    int ct0 = wave * 2; \
    bf16x8 bh[2][8], bl[2][8]; \
    _Pragma("unroll") \
    for (int c = 0; c < 2; ++c) \
        _Pragma("unroll") \
        for (int kc = 0; kc < 8; ++kc) { \
            size_t widx = (size_t)((ct0 + c) * 16 + row) * 256 + kc * 32 + kb * 8; \
            bh[c][kc] = *(const bf16x8*)(Whi + widx); \
            bl[c][kc] = *(const bf16x8*)(Wlo + widx); \
        } \
    float b0 = bias[ct0 * 16 + row]; \
    float b1 = bias[ct0 * 16 + 16 + row];

#define LOADT(AS, AH, AL, t) { \
        size_t rb = (size_t)((t) * 16 + row) * 128 + kb * 8; \
        _Pragma("unroll") \
        for (int kc = 0; kc < 4; ++kc) { \
            AS[kc] = *(const bf16x8*)(Ash + rb + kc * 32); \
            AH[kc] = *(const bf16x8*)(Ahh + rb + kc * 32); \
            AL[kc] = *(const bf16x8*)(Ahl + rb + kc * 32); \
        } }

#define MFMA40(AS, AH, AL) \
        f32x4 acc0 = {0.f, 0.f, 0.f, 0.f}; \
        f32x4 acc1 = {0.f, 0.f, 0.f, 0.f}; \
        _Pragma("unroll") \
        for (int kc = 0; kc < 4; ++kc) { \
            acc0 = __builtin_amdgcn_mfma_f32_16x16x32_bf16(AS[kc], bh[0][kc], acc0, 0, 0, 0); \
            acc0 = __builtin_amdgcn_mfma_f32_16x16x32_bf16(AS[kc], bl[0][kc], acc0, 0, 0, 0); \
            acc1 = __builtin_amdgcn_mfma_f32_16x16x32_bf16(AS[kc], bh[1][kc], acc1, 0, 0, 0); \
            acc1 = __builtin_amdgcn_mfma_f32_16x16x32_bf16(AS[kc], bl[1][kc], acc1, 0, 0, 0); \
        } \
        _Pragma("unroll") \
        for (int kc = 0; kc < 4; ++kc) { \
            acc0 = __builtin_amdgcn_mfma_f32_16x16x32_bf16(AH[kc], bh[0][4 + kc], acc0, 0, 0, 0); \
            acc0 = __builtin_amdgcn_mfma_f32_16x16x32_bf16(AL[kc], bh[0][4 + kc], acc0, 0, 0, 0); \
            acc0 = __builtin_amdgcn_mfma_f32_16x16x32_bf16(AH[kc], bl[0][4 + kc], acc0, 0, 0, 0); \
            acc1 = __builtin_amdgcn_mfma_f32_16x16x32_bf16(AH[kc], bh[1][4 + kc], acc1, 0, 0, 0); \
            acc1 = __builtin_amdgcn_mfma_f32_16x16x32_bf16(AL[kc], bh[1][4 + kc], acc1, 0, 0, 0); \
            acc1 = __builtin_amdgcn_mfma_f32_16x16x32_bf16(AH[kc], bl[1][4 + kc], acc1, 0, 0, 0); \
        }

__global__ __launch_bounds__(256, 2) void k_gemm_ws(
        const unsigned short* __restrict__ Ash,
        const unsigned short* __restrict__ Ahh, const unsigned short* __restrict__ Ahl,
        const unsigned short* __restrict__ Whi, const unsigned short* __restrict__ Wlo,
        const float* __restrict__ bias,
        unsigned short* __restrict__ Ohi, unsigned short* __restrict__ Olo) {
    GEMM_PROLOG
#define STEP(AS, AH, AL, t) { \
        MFMA40(AS, AH, AL) \
        __syncthreads();   /* all waves' reads of tile t precede its writes */ \
        int cb0 = ct0 * 16 + row; \
        _Pragma("unroll") \
        for (int r = 0; r < 4; ++r) { \
            size_t ro = (size_t)((t) * 16 + kb * 4 + r) * 128; \
            unsigned p0 = pack_split(fmaxf(acc0[r] + b0, 0.f)); \
            unsigned p1 = pack_split(fmaxf(acc1[r] + b1, 0.f)); \
            Ohi[ro + cb0]      = (unsigned short)(p0 >> 16); \
            Olo[ro + cb0]      = (unsigned short)(p0 & 0xFFFFu); \
            Ohi[ro + cb0 + 16] = (unsigned short)(p1 >> 16); \
            Olo[ro + cb0 + 16] = (unsigned short)(p1 & 0xFFFFu); \
        } }
    bf16x8 sA[4], hA[4], lA[4], sB[4], hB[4], lB[4];
    int t = blockIdx.x;
    LOADT(sA, hA, lA, t)
    int tn = t + GGRID;
    for (;;) {
        if (tn < NTILE) LOADT(sB, hB, lB, tn)
        STEP(sA, hA, lA, t)
        if (tn >= NTILE) break;
        t = tn; tn += GGRID;
        if (tn < NTILE) LOADT(sA, hA, lA, tn)
        STEP(sB, hB, lB, t)
        if (tn >= NTILE) break;
        t = tn; tn += GGRID;
    }
#undef STEP
}

// layer-2 variant: head fused — out[n] += sum_c relu(h3[n][c]) * Wf[c]
__global__ __launch_bounds__(256, 2) void k_gemm_head(
        const unsigned short* __restrict__ Ash,
        const unsigned short* __restrict__ Ahh, const unsigned short* __restrict__ Ahl,
        const unsigned short* __restrict__ Whi, const unsigned short* __restrict__ Wlo,
        const float* __restrict__ bias, const float* __restrict__ Wf,
        float* __restrict__ out) {
    GEMM_PROLOG
    float w0 = Wf[ct0 * 16 + row];
    float w1 = Wf[ct0 * 16 + 16 + row];
#define HSTEP(AS, AH, AL, t) { \
        MFMA40(AS, AH, AL) \
        float part[4]; \
        _Pragma("unroll") \
        for (int r = 0; r < 4; ++r) \
            part[r] = fmaxf(acc0[r] + b0, 0.f) * w0 + fmaxf(acc1[r] + b1, 0.f) * w1; \
        _Pragma("unroll") \
        for (int o = 1; o < 16; o <<= 1) { \
            _Pragma("unroll") \
            for (int r = 0; r < 4; ++r) part[r] += __shfl_xor(part[r], o); \
        } \
        if (row == 0) { \
            _Pragma("unroll") \
            for (int r = 0; r < 4; ++r) atomicAdd(&out[(t) * 16 + kb * 4 + r], part[r]); \
        } }
    bf16x8 sA[4], hA[4], lA[4], sB[4], hB[4], lB[4];
    int t = blockIdx.x;
    LOADT(sA, hA, lA, t)
    int tn = t + GGRID;
    for (;;) {
        if (tn < NTILE) LOADT(sB, hB, lB, tn)
        HSTEP(sA, hA, lA, t)
        if (tn >= NTILE) break;
        t = tn; tn += GGRID;
        if (tn < NTILE) LOADT(sA, hA, lA, tn)
        HSTEP(sB, hB, lB, t)
        if (tn >= NTILE) break;
        t = tn; tn += GGRID;
    }
#undef HSTEP
}

extern "C" void kernel_launch(void* const* d_in, const int* in_sizes, int n_in,
                              void* d_out, int out_size, void* d_ws, size_t ws_size,
                              hipStream_t stream) {
    const float* x   = (const float*)d_in[0];
    const int*   ei  = (const int*)d_in[1];
    const float* Wl0 = (const float*)d_in[2];
    const float* bl0 = (const float*)d_in[3];
    const float* Wr0 = (const float*)d_in[4];
    const float* Wl1 = (const float*)d_in[5];
    const float* bl1 = (const float*)d_in[6];
    const float* Wr1 = (const float*)d_in[7];
    const float* Wl2 = (const float*)d_in[8];
    const float* bl2 = (const float*)d_in[9];
    const float* Wr2 = (const float*)d_in[10];
    const float* Wf  = (const float*)d_in[11];
    const float* bf  = (const float*)d_in[12];
    float* out = (float*)d_out;

    char* p = (char*)d_ws;
    auto alloc = [&](size_t n) { void* r = (void*)p; p += (n + 255) & ~(size_t)255; return r; };
    int*            bcnt      = (int*)alloc(256 * 4);
    int*            cnt       = (int*)alloc((size_t)NN * 4);
    int*            ecnt      = (int*)alloc((size_t)NGRP * 4);
    unsigned*       perm32    = (unsigned*)alloc((size_t)NGRP * HCAP * 4);
    unsigned short* s_hi      = (unsigned short*)alloc((size_t)(NN + 1) * 128 * 2);
    unsigned short* h_hi      = (unsigned short*)alloc((size_t)(NN + 1) * 128 * 2);
    unsigned short* h_lo      = (unsigned short*)alloc((size_t)(NN + 1) * 128 * 2);
    unsigned short* whi       = (unsigned short*)alloc((size_t)3 * 128 * 256 * 2);
    unsigned short* wlo       = (unsigned short*)alloc((size_t)3 * 128 * 256 * 2);
    unsigned*       packed    = (unsigned*)s_hi;  // 4.8MB < 12.8MB; consumed
                                                  // by bucket_csr before agg

    dim3 b256(256);
    // pack x + all init (out bias, bcnt, sentinel row) — must precede build
    k_packinit<<<dim3((NN * 128 / 4 + 255) / 256), b256, 0, stream>>>(
        x, h_hi, h_lo, out, bf, bcnt);
    // CSR build: 2 kernels
    k_build_buckets<<<dim3(NBLK), b256, 0, stream>>>(ei, bcnt, packed);
    k_bucket_csr<<<dim3(NBUCK), b256, 0, stream>>>(packed, bcnt, perm32, cnt, ecnt);
    // weights (all 3 layers, 1 kernel)
    k_pack_w3<<<dim3(384), b256, 0, stream>>>(Wl0, Wr0, Wl1, Wr1, Wl2, Wr2, whi, wlo);

    dim3 gAgg(NGRP);            // 1568 groups, all co-resident (8 blocks/CU)
    dim3 gGemm(GGRID);          // 2 blocks/CU; grid-stride over 3125 tiles

    // layer 0
    k_aggregate<<<gAgg, b256, 0, stream>>>(h_hi, cnt, perm32, ecnt, s_hi);
    k_gemm_ws<<<gGemm, b256, 0, stream>>>(s_hi, h_hi, h_lo,
                                          whi + 0 * 32768, wlo + 0 * 32768, bl0, h_hi, h_lo);
    // layer 1 (in place)
    k_aggregate<<<gAgg, b256, 0, stream>>>(h_hi, cnt, perm32, ecnt, s_hi);
    k_gemm_ws<<<gGemm, b256, 0, stream>>>(s_hi, h_hi, h_lo,
                                          whi + 1 * 32768, wlo + 1 * 32768, bl1, h_hi, h_lo);
    // layer 2 + fused head
    k_aggregate<<<gAgg, b256, 0, stream>>>(h_hi, cnt, perm32, ecnt, s_hi);
    k_gemm_head<<<gGemm, b256, 0, stream>>>(s_hi, h_hi, h_lo,
                                            whi + 2 * 32768, wlo + 2 * 32768, bl2, Wf, out);
}

// Round 5
// 283.938 us; speedup vs baseline: 7.1857x; 7.1857x over previous
//
#include <hip/hip_runtime.h>
#include <hip/hip_bf16.h>

// GraphSage: 3x SAGEConv(mean) + linear head.
// r22: REVERT to r19 structure (best measured: 284.7us) + pack_w fused into
//   packinit (launches 10 -> 9). No other changes.
//   - r20 POST-MORTEM: per-node insertion sort cost +44us (divergent LDS
//     O(deg^2), 1.6M bank conflicts), gather gained 0. Per-node sorted lists
//     do not form a coherent window (degree variance disperses progress).
//   - r21 POST-MORTEM: LDS-atomic scatter aggregate = 611us/dispatch
//     (serialization on ds_add_f32 atomics + bank contention, hbm 1.8%).
//     Locality transforms cost more than the L2-miss penalty they recover.
//   - CONCLUSION (do not retry): aggregate gather (padded CSR, 1 node/wave,
//     uint4 gathers) runs >=4.8 TB/s effective, within ~25% of streaming
//     ceiling. Aggregate is at its practical byte-floor.
// r19 structure: aggregate gathers ONLY the hi plane; CSR rows padded to
//   mult of 8 with sentinel src=NN (zeroed row, L1-resident) -> no tail
//   loops; uint4 gather: lane=(edge group, col chunk), one wave-load = FOUR
//   256B rows; GEMM double-buffers the A-tile across the grid-stride loop
//   (prefetch t+512 before MFMA(t); in-place safe: tile t+512's rows are
//   written only by this same block, later); s_lo plane dropped (mean is
//   bf16-precision anyway; ~2.3e-4/layer quadrature error).
// CSR build: fixed bucket regions + LDS hist + one atomicAdd range reserve.
// Structure: SEPARATE aggregate and GEMM (r12 fusion starved the gather).
// XCD affinity NOT controllable from HIP (r14/r15) — do not retry.
// fp8 gather REJECTED: mean-of-16 e4m3 noise ~4.3e-3 > 3.85e-3 threshold.
// packed[] aliases s_hi (disjoint lifetime: consumed by bucket_csr pre-agg).

constexpr int NN = 50000;
constexpr int NE = 800000;
constexpr int NTILE = NN / 16;          // 3125 exact
constexpr int EPB = 4096;
constexpr int NBLK = (NE + EPB - 1) / EPB;   // 196
constexpr int NBUCK = 196;                   // ceil(NN/256)
constexpr int BCAP = 6144;   // packed bucket capacity (edges); mean 4096
constexpr int PCAP = 6144;   // padded perm bucket capacity; mean ~4992, mult of 8
constexpr int GGRID = 512;   // GEMM grid (2 blocks/CU)
constexpr int XBLK = (NN * 128 / 4 + 255) / 256;   // 6250 x-pack blocks

using bf16x8 = __attribute__((ext_vector_type(8))) short;
using f32x4  = __attribute__((ext_vector_type(4))) float;

__device__ __forceinline__ unsigned short bf16_rne(float f) {
    unsigned u = __float_as_uint(f);
    unsigned r = (u + 0x7FFFu + ((u >> 16) & 1u)) >> 16;
    return (unsigned short)r;
}
__device__ __forceinline__ float bf16_f(unsigned short h) {
    return __uint_as_float(((unsigned)h) << 16);
}
__device__ __forceinline__ unsigned pack_split(float v) {
    unsigned short hi = bf16_rne(v);
    float r = v - bf16_f(hi);
    unsigned short lo = bf16_rne(r);
    return (((unsigned)hi) << 16) | (unsigned)lo;
}

// --- pack x -> planar split bf16, init work, and all 3 weight packs -------
// blocks [0, XBLK): x-pack + out-bias + bcnt + sentinel row
// blocks [XBLK, XBLK+384): weight split-pack (layer = idx>>15)

__global__ __launch_bounds__(256) void k_packinit(const float* __restrict__ x,
        unsigned short* __restrict__ hhi, unsigned short* __restrict__ hlo,
        float* __restrict__ out, const float* __restrict__ bf,
        int* __restrict__ bcnt,
        const float* __restrict__ Wl0, const float* __restrict__ Wr0,
        const float* __restrict__ Wl1, const float* __restrict__ Wr1,
        const float* __restrict__ Wl2, const float* __restrict__ Wr2,
        unsigned short* __restrict__ whi, unsigned short* __restrict__ wlo) {
    if (blockIdx.x >= XBLK) {
        int gi = (blockIdx.x - XBLK) * 256 + threadIdx.x;  // 0..98303
        int layer = gi >> 15;
        int i = gi & 32767;
        const float* Wl = (layer == 0) ? Wl0 : (layer == 1) ? Wl1 : Wl2;
        const float* Wr = (layer == 0) ? Wr0 : (layer == 1) ? Wr1 : Wr2;
        int c = i >> 8;
        int k = i & 255;
        float v = (k < 128) ? Wl[c * 128 + k] : Wr[c * 128 + (k - 128)];
        unsigned short hi = bf16_rne(v);
        whi[gi] = hi;
        wlo[gi] = bf16_rne(v - bf16_f(hi));
        return;
    }
    int i = blockIdx.x * blockDim.x + threadIdx.x;
    constexpr int TOT = NN * 128 / 4;
    if (i < TOT) {
        float4 v = ((const float4*)x)[i];
        unsigned p0 = pack_split(v.x), p1 = pack_split(v.y);
        unsigned p2 = pack_split(v.z), p3 = pack_split(v.w);
        uint2 hi, lo;
        hi.x = (p0 >> 16) | (p1 & 0xFFFF0000u);
        hi.y = (p2 >> 16) | (p3 & 0xFFFF0000u);
        lo.x = (p0 & 0xFFFFu) | (p1 << 16);
        lo.y = (p2 & 0xFFFFu) | (p3 << 16);
        ((uint2*)hhi)[i] = hi;
        ((uint2*)hlo)[i] = lo;
    }
    if (i < NN) out[i] = bf[0];
    if (i < 256) bcnt[i] = 0;
    if (i < 128) hhi[(size_t)NN * 128 + i] = 0;   // sentinel row for pad edges
}

// ---------------- CSR build: one-pass bucket scatter ----------------

__global__ __launch_bounds__(256) void k_build_buckets(const int* __restrict__ ei,
        int* __restrict__ bcnt, unsigned* __restrict__ packed) {
    __shared__ unsigned stage[EPB];   // 16KB
    __shared__ int h[256];
    __shared__ int cur[256];
    int t = threadIdx.x;
    h[t] = 0;
    __syncthreads();
    int e0 = blockIdx.x * EPB;
    int e1 = e0 + EPB; if (e1 > NE) e1 = NE;
    for (int e = e0 + t; e < e1; e += 256) {
        int s = ei[e];
        int d = ei[NE + e];
        stage[e - e0] = ((unsigned)d << 16) | (unsigned)s;
        atomicAdd(&h[d >> 8], 1);
    }
    __syncthreads();
    if (t < NBUCK) cur[t] = t * BCAP + atomicAdd(&bcnt[t], h[t]);
    __syncthreads();
    for (int e = e0 + t; e < e1; e += 256) {
        unsigned r = stage[e - e0];
        int pos = atomicAdd(&cur[r >> 24], 1);   // bucket = d>>8 = r>>24
        packed[pos] = r;
    }
}

// Per bucket: LDS counting sort by (d&255) with per-node padding to mult of 8;
// pad slots filled with sentinel NN. row_start points into b*PCAP region.
__global__ __launch_bounds__(256) void k_bucket_csr(const unsigned* __restrict__ packed,
        const int* __restrict__ bcnt, unsigned short* __restrict__ perm,
        int* __restrict__ cnt, int* __restrict__ row_start) {
    __shared__ unsigned recs[BCAP];       // 24KB
    __shared__ unsigned short outs[PCAP]; // 12KB
    __shared__ int cntL[256];
    __shared__ int ws[4];
    __shared__ int totS;
    int b = blockIdx.x;
    int m = bcnt[b];
    if (m > BCAP) m = BCAP;
    int t = threadIdx.x;
    cntL[t] = 0;
    __syncthreads();
    int lo = b * BCAP;
    for (int i = t; i < m; i += 256) {
        unsigned r = packed[lo + i];
        recs[i] = r;
        atomicAdd(&cntL[(r >> 16) & 255], 1);
    }
    __syncthreads();
    int lane = t & 63, wave = t >> 6;
    int orig = cntL[t];
    int pc = (orig + 7) & ~7;            // padded per-node degree
    int v = pc;
    for (int o = 1; o < 64; o <<= 1) { int u = __shfl_up(v, o); if (lane >= o) v += u; }
    if (lane == 63) ws[wave] = v;
    __syncthreads();
    int off = 0;
    for (int w = 0; w < wave; ++w) off += ws[w];
    int st = v + off - pc;               // exclusive scan of padded degrees
    int node = b * 256 + t;
    if (node < NN) { cnt[node] = orig; row_start[node] = b * PCAP + st; }
    if (t == 255) totS = st + pc;
    __syncthreads();
    cntL[t] = st;
    __syncthreads();
    for (int i = t; i < m; i += 256) {
        unsigned r = recs[i];
        int pos = atomicAdd(&cntL[(r >> 16) & 255], 1);
        outs[pos] = (unsigned short)(r & 0xFFFFu);
    }
    // pad fill: disjoint from scatter's target region, no barrier needed
    for (int i = st + orig; i < st + pc; ++i) outs[i] = (unsigned short)NN;
    __syncthreads();
    int totp = totS;
    for (int i = t; i < totp; i += 256)
        perm[b * PCAP + i] = outs[i];
}

// ---------------- aggregate (mean over padded CSR, hi-plane only) ----------
// 1 node/wave. lane = (eg = lane>>4: edge group, cl = lane&15: 16B col chunk).
// One uint4 wave-load covers FOUR 256B rows. eg-reduce = shfl_xor 16, 32.
__global__ __launch_bounds__(256) void k_aggregate(const unsigned short* __restrict__ hhi,
        const int* __restrict__ row_start, const int* __restrict__ cnt,
        const unsigned short* __restrict__ perm,
        unsigned short* __restrict__ shi) {
    int wave = __builtin_amdgcn_readfirstlane(threadIdx.x >> 6);
    int lane = threadIdx.x & 63;
    int node = blockIdx.x * 4 + wave;
    if (node >= NN) return;
    int deg = cnt[node];
    int start = row_start[node];              // multiple of 8 -> 16B aligned
    int eg = lane >> 4;
    int hsh = (eg & 1) << 4;                  // ushort half within u32
    bool egHi = (eg & 2) != 0;                // which u32 of the pair
    int c16 = (lane & 15) << 4;               // byte offset of uint4 in row
    const char* base = (const char*)hhi;      // row stride 256B
    float a0=0.f,a1=0.f,a2=0.f,a3=0.f,a4=0.f,a5=0.f,a6=0.f,a7=0.f;
#define ACC8(q) { a0 += __uint_as_float((q).x << 16); a1 += __uint_as_float((q).x & 0xFFFF0000u); \
                  a2 += __uint_as_float((q).y << 16); a3 += __uint_as_float((q).y & 0xFFFF0000u); \
                  a4 += __uint_as_float((q).z << 16); a5 += __uint_as_float((q).z & 0xFFFF0000u); \
                  a6 += __uint_as_float((q).w << 16); a7 += __uint_as_float((q).w & 0xFFFF0000u); }
#define GATH(w) (*(const uint4*)(base + ((size_t)(((w) >> hsh) & 0xFFFFu) << 8) + c16))
    int pdeg = (deg + 7) & ~7;
    const uint4* pp = (const uint4*)(perm + start);
    int j = 0;
    for (; j + 16 <= pdeg; j += 16) {
        uint4 P0 = pp[0], P1 = pp[1]; pp += 2;
        unsigned w0 = egHi ? P0.y : P0.x;     // edges j+0+eg
        unsigned w1 = egHi ? P0.w : P0.z;     // edges j+4+eg
        unsigned w2 = egHi ? P1.y : P1.x;     // edges j+8+eg
        unsigned w3 = egHi ? P1.w : P1.z;     // edges j+12+eg
        uint4 q0 = GATH(w0);
        uint4 q1 = GATH(w1);
        uint4 q2 = GATH(w2);
        uint4 q3 = GATH(w3);
        ACC8(q0); ACC8(q1); ACC8(q2); ACC8(q3);
    }
    if (j < pdeg) {                           // exactly one 8-edge step
        uint4 P0 = *pp;
        unsigned w0 = egHi ? P0.y : P0.x;
        unsigned w1 = egHi ? P0.w : P0.z;
        uint4 q0 = GATH(w0);
        uint4 q1 = GATH(w1);
        ACC8(q0); ACC8(q1);
    }
#undef GATH
#undef ACC8
    // reduce across the 4 edge groups (^16 flips eg bit0, ^32 flips bit1)
    a0 += __shfl_xor(a0, 16); a1 += __shfl_xor(a1, 16);
    a2 += __shfl_xor(a2, 16); a3 += __shfl_xor(a3, 16);
    a4 += __shfl_xor(a4, 16); a5 += __shfl_xor(a5, 16);
    a6 += __shfl_xor(a6, 16); a7 += __shfl_xor(a7, 16);
    a0 += __shfl_xor(a0, 32); a1 += __shfl_xor(a1, 32);
    a2 += __shfl_xor(a2, 32); a3 += __shfl_xor(a3, 32);
    a4 += __shfl_xor(a4, 32); a5 += __shfl_xor(a5, 32);
    a6 += __shfl_xor(a6, 32); a7 += __shfl_xor(a7, 32);
    float inv = 1.0f / (float)(deg > 1 ? deg : 1);
    if (eg == 0) {
        uint4 o;
        o.x = (unsigned)bf16_rne(a0 * inv) | ((unsigned)bf16_rne(a1 * inv) << 16);
        o.y = (unsigned)bf16_rne(a2 * inv) | ((unsigned)bf16_rne(a3 * inv) << 16);
        o.z = (unsigned)bf16_rne(a4 * inv) | ((unsigned)bf16_rne(a5 * inv) << 16);
        o.w = (unsigned)bf16_rne(a6 * inv) | ((unsigned)bf16_rne(a7 * inv) << 16);
        ((uint4*)shi)[(size_t)node * 16 + (lane & 15)] = o;
    }
}

// ---------------- weight-stationary MFMA GEMM (pipelined grid-stride) ------
// out[n][c] = relu( bias[c] + sum_k [S|H][n][k] W[c][k] )
// A = {s_hi (mean, bf16), h_hi+h_lo (x, split)}. 12 dwordx4 A loads/tile,
// double-buffered across the grid-stride loop (prefetch t+512 before MFMA(t)).
#define GEMM_PROLOG \
    int wave = __builtin_amdgcn_readfirstlane(threadIdx.x >> 6); \
    int lane = threadIdx.x & 63; \
    int row = lane & 15; \
    int kb = lane >> 4; \
    int ct0 = wave * 2; \
    bf16x8 bh[2][8], bl[2][8]; \
    _Pragma("unroll") \
    for (int c = 0; c < 2; ++c) \
        _Pragma("unroll") \
        for (int kc = 0; kc < 8; ++kc) { \
            size_t widx = (size_t)((ct0 + c) * 16 + row) * 256 + kc * 32 + kb * 8; \
            bh[c][kc] = *(const bf16x8*)(Whi + widx); \
            bl[c][kc] = *(const bf16x8*)(Wlo + widx); \
        } \
    float b0 = bias[ct0 * 16 + row]; \
    float b1 = bias[ct0 * 16 + 16 + row];

#define LOADT(AS, AH, AL, t) { \
        size_t rb = (size_t)((t) * 16 + row) * 128 + kb * 8; \
        _Pragma("unroll") \
        for (int kc = 0; kc < 4; ++kc) { \
            AS[kc] = *(const bf16x8*)(Ash + rb + kc * 32); \
            AH[kc] = *(const bf16x8*)(Ahh + rb + kc * 32); \
            AL[kc] = *(const bf16x8*)(Ahl + rb + kc * 32); \
        } }

#define MFMA40(AS, AH, AL) \
        f32x4 acc0 = {0.f, 0.f, 0.f, 0.f}; \
        f32x4 acc1 = {0.f, 0.f, 0.f, 0.f}; \
        _Pragma("unroll") \
        for (int kc = 0; kc < 4; ++kc) { \
            acc0 = __builtin_amdgcn_mfma_f32_16x16x32_bf16(AS[kc], bh[0][kc], acc0, 0, 0, 0); \
            acc0 = __builtin_amdgcn_mfma_f32_16x16x32_bf16(AS[kc], bl[0][kc], acc0, 0, 0, 0); \
            acc1 = __builtin_amdgcn_mfma_f32_16x16x32_bf16(AS[kc], bh[1][kc], acc1, 0, 0, 0); \
            acc1 = __builtin_amdgcn_mfma_f32_16x16x32_bf16(AS[kc], bl[1][kc], acc1, 0, 0, 0); \
        } \
        _Pragma("unroll") \
        for (int kc = 0; kc < 4; ++kc) { \
            acc0 = __builtin_amdgcn_mfma_f32_16x16x32_bf16(AH[kc], bh[0][4 + kc], acc0, 0, 0, 0); \
            acc0 = __builtin_amdgcn_mfma_f32_16x16x32_bf16(AL[kc], bh[0][4 + kc], acc0, 0, 0, 0); \
            acc0 = __builtin_amdgcn_mfma_f32_16x16x32_bf16(AH[kc], bl[0][4 + kc], acc0, 0, 0, 0); \
            acc1 = __builtin_amdgcn_mfma_f32_16x16x32_bf16(AH[kc], bh[1][4 + kc], acc1, 0, 0, 0); \
            acc1 = __builtin_amdgcn_mfma_f32_16x16x32_bf16(AL[kc], bh[1][4 + kc], acc1, 0, 0, 0); \
            acc1 = __builtin_amdgcn_mfma_f32_16x16x32_bf16(AH[kc], bl[1][4 + kc], acc1, 0, 0, 0); \
        }

__global__ __launch_bounds__(256, 2) void k_gemm_ws(
        const unsigned short* __restrict__ Ash,
        const unsigned short* __restrict__ Ahh, const unsigned short* __restrict__ Ahl,
        const unsigned short* __restrict__ Whi, const unsigned short* __restrict__ Wlo,
        const float* __restrict__ bias,
        unsigned short* __restrict__ Ohi, unsigned short* __restrict__ Olo) {
    GEMM_PROLOG
#define STEP(AS, AH, AL, t) { \
        MFMA40(AS, AH, AL) \
        __syncthreads();   /* all waves' reads of tile t precede its writes */ \
        int cb0 = ct0 * 16 + row; \
        _Pragma("unroll") \
        for (int r = 0; r < 4; ++r) { \
            size_t ro = (size_t)((t) * 16 + kb * 4 + r) * 128; \
            unsigned p0 = pack_split(fmaxf(acc0[r] + b0, 0.f)); \
            unsigned p1 = pack_split(fmaxf(acc1[r] + b1, 0.f)); \
            Ohi[ro + cb0]      = (unsigned short)(p0 >> 16); \
            Olo[ro + cb0]      = (unsigned short)(p0 & 0xFFFFu); \
            Ohi[ro + cb0 + 16] = (unsigned short)(p1 >> 16); \
            Olo[ro + cb0 + 16] = (unsigned short)(p1 & 0xFFFFu); \
        } }
    bf16x8 sA[4], hA[4], lA[4], sB[4], hB[4], lB[4];
    int t = blockIdx.x;
    LOADT(sA, hA, lA, t)
    int tn = t + GGRID;
    for (;;) {
        if (tn < NTILE) LOADT(sB, hB, lB, tn)
        STEP(sA, hA, lA, t)
        if (tn >= NTILE) break;
        t = tn; tn += GGRID;
        if (tn < NTILE) LOADT(sA, hA, lA, tn)
        STEP(sB, hB, lB, t)
        if (tn >= NTILE) break;
        t = tn; tn += GGRID;
    }
#undef STEP
}

// layer-2 variant: head fused — out[n] += sum_c relu(h3[n][c]) * Wf[c]
__global__ __launch_bounds__(256, 2) void k_gemm_head(
        const unsigned short* __restrict__ Ash,
        const unsigned short* __restrict__ Ahh, const unsigned short* __restrict__ Ahl,
        const unsigned short* __restrict__ Whi, const unsigned short* __restrict__ Wlo,
        const float* __restrict__ bias, const float* __restrict__ Wf,
        float* __restrict__ out) {
    GEMM_PROLOG
    float w0 = Wf[ct0 * 16 + row];
    float w1 = Wf[ct0 * 16 + 16 + row];
#define HSTEP(AS, AH, AL, t) { \
        MFMA40(AS, AH, AL) \
        float part[4]; \
        _Pragma("unroll") \
        for (int r = 0; r < 4; ++r) \
            part[r] = fmaxf(acc0[r] + b0, 0.f) * w0 + fmaxf(acc1[r] + b1, 0.f) * w1; \
        _Pragma("unroll") \
        for (int o = 1; o < 16; o <<= 1) { \
            _Pragma("unroll") \
            for (int r = 0; r < 4; ++r) part[r] += __shfl_xor(part[r], o); \
        } \
        if (row == 0) { \
            _Pragma("unroll") \
            for (int r = 0; r < 4; ++r) atomicAdd(&out[(t) * 16 + kb * 4 + r], part[r]); \
        } }
    bf16x8 sA[4], hA[4], lA[4], sB[4], hB[4], lB[4];
    int t = blockIdx.x;
    LOADT(sA, hA, lA, t)
    int tn = t + GGRID;
    for (;;) {
        if (tn < NTILE) LOADT(sB, hB, lB, tn)
        HSTEP(sA, hA, lA, t)
        if (tn >= NTILE) break;
        t = tn; tn += GGRID;
        if (tn < NTILE) LOADT(sA, hA, lA, tn)
        HSTEP(sB, hB, lB, t)
        if (tn >= NTILE) break;
        t = tn; tn += GGRID;
    }
#undef HSTEP
}

extern "C" void kernel_launch(void* const* d_in, const int* in_sizes, int n_in,
                              void* d_out, int out_size, void* d_ws, size_t ws_size,
                              hipStream_t stream) {
    const float* x   = (const float*)d_in[0];
    const int*   ei  = (const int*)d_in[1];
    const float* Wl0 = (const float*)d_in[2];
    const float* bl0 = (const float*)d_in[3];
    const float* Wr0 = (const float*)d_in[4];
    const float* Wl1 = (const float*)d_in[5];
    const float* bl1 = (const float*)d_in[6];
    const float* Wr1 = (const float*)d_in[7];
    const float* Wl2 = (const float*)d_in[8];
    const float* bl2 = (const float*)d_in[9];
    const float* Wr2 = (const float*)d_in[10];
    const float* Wf  = (const float*)d_in[11];
    const float* bf  = (const float*)d_in[12];
    float* out = (float*)d_out;

    char* p = (char*)d_ws;
    auto alloc = [&](size_t n) { void* r = (void*)p; p += (n + 255) & ~(size_t)255; return r; };
    int*            bcnt      = (int*)alloc(256 * 4);
    int*            cnt       = (int*)alloc((size_t)NN * 4);
    int*            row_start = (int*)alloc((size_t)NN * 4);
    unsigned short* perm      = (unsigned short*)alloc((size_t)NBUCK * PCAP * 2);
    unsigned short* s_hi      = (unsigned short*)alloc((size_t)(NN + 1) * 128 * 2);
    unsigned short* h_hi      = (unsigned short*)alloc((size_t)(NN + 1) * 128 * 2);
    unsigned short* h_lo      = (unsigned short*)alloc((size_t)(NN + 1) * 128 * 2);
    unsigned short* whi       = (unsigned short*)alloc((size_t)3 * 128 * 256 * 2);
    unsigned short* wlo       = (unsigned short*)alloc((size_t)3 * 128 * 256 * 2);
    unsigned*       packed    = (unsigned*)s_hi;  // 4.8MB < 12.8MB; consumed
                                                  // by bucket_csr before agg

    dim3 b256(256);
    // pack x + weights + all init (out bias, bcnt, sentinel) — precedes build
    k_packinit<<<dim3(XBLK + 384), b256, 0, stream>>>(
        x, h_hi, h_lo, out, bf, bcnt,
        Wl0, Wr0, Wl1, Wr1, Wl2, Wr2, whi, wlo);
    // CSR build: 2 kernels
    k_build_buckets<<<dim3(NBLK), b256, 0, stream>>>(ei, bcnt, packed);
    k_bucket_csr<<<dim3(NBUCK), b256, 0, stream>>>(packed, bcnt, perm, cnt, row_start);

    dim3 gAgg((NN + 3) / 4);    // 1 node/wave, 4 per block
    dim3 gGemm(GGRID);          // 2 blocks/CU; grid-stride over 3125 tiles

    // layer 0
    k_aggregate<<<gAgg, b256, 0, stream>>>(h_hi, row_start, cnt, perm, s_hi);
    k_gemm_ws<<<gGemm, b256, 0, stream>>>(s_hi, h_hi, h_lo,
                                          whi + 0 * 32768, wlo + 0 * 32768, bl0, h_hi, h_lo);
    // layer 1 (in place)
    k_aggregate<<<gAgg, b256, 0, stream>>>(h_hi, row_start, cnt, perm, s_hi);
    k_gemm_ws<<<gGemm, b256, 0, stream>>>(s_hi, h_hi, h_lo,
                                          whi + 1 * 32768, wlo + 1 * 32768, bl1, h_hi, h_lo);
    // layer 2 + fused head
    k_aggregate<<<gAgg, b256, 0, stream>>>(h_hi, row_start, cnt, perm, s_hi);
    k_gemm_head<<<gGemm, b256, 0, stream>>>(s_hi, h_hi, h_lo,
                                            whi + 2 * 32768, wlo + 2 * 32768, bl2, Wf, out);
}